// Round 12
// baseline (84.262 us; speedup 1.0000x reference)
//
#include <hip/hip_runtime.h>

// Problem constants (fixed by reference)
#define CIN     32
#define COUT    64
#define OUT_DIM 1024
#define RS4     1024           // float4 per (.,c) row (4096 floats)

// out[b,o,p] = (1/sqrt(32)) * sum_{c,k} x[b,c,4p+k] * w[o,c,4p+k]
//
// v14: v13's bytes (w staged once, x 4x through XCD-L2, o-tile 16, all b,
// everything computed from LDS) with the two residual weaknesses fixed:
//   1. v13 ran ONE 512-thread block/CU -> 2 waves/SIMD; the LDS-only
//      compute (ds_read -> FMA chains) was latency-exposed.
//   2. whole-CU lockstep barriers: any delivery tail stalled the CU.
// v14: 8-patch tiles -> 512 blocks = 2 blocks/CU (32 KB LDS each), 4-c
// chunks double-buffered (8 iters), 16 waves/CU = 4 waves/SIMD. The two
// resident blocks barrier independently: when one waits on vmcnt, the
// other computes -> smooth HBM demand + hidden LDS latency.
// Per iter: stage(ci+1) via global_load_lds (wave-uniform linear dest,
// 1 KB/instr = 8 rows x 128 B), compute(ci) from LDS only (v6's FIFO-vmcnt
// trap structurally absent), one barrier.
// Grid 512 = 4 og x 128 pc; swizzle: 4 og-siblings of a pc + 16
// consecutive pc share an XCD (x per XCD = 1 MB, L2-resident).
__global__ __launch_bounds__(512, 4) void nolc1d_kernel(
    const float* __restrict__ x,
    const float* __restrict__ w,
    float* __restrict__ out)
{
    const int bid = blockIdx.x;
    const int xcd = bid & 7;
    const int m   = bid >> 3;               // 0..63
    const int og  = m & 3;                  // o-group 0..3 (16 o each)
    const int pc  = xcd * 16 + (m >> 2);    // patch-chunk 0..127 (8 p each)
    const int o0  = og * 16;
    const int pf0 = pc * 8;                 // f4 (=patch) column base

    const int t    = threadIdx.x;           // = oq*128 + g5*32 + cs*8 + p
    const int lane = t & 63;
    const int wv   = t >> 6;                // wave 0..7
    const int p    = t & 7;                 // patch within tile
    const int cs   = (t >> 3) & 3;          // c-split 4-way (1 c/chunk)
    const int g    = (t >> 5) & 3;          // b-quad (b = 4g+bi)
    const int oq   = t >> 7;                // o-quad (o = o0+4oq+oi)

    // [buf][(hi*4 + cl)*8 + q]: hi = ol (w) / b (x), cl = c within chunk,
    // q = f4 column. 512 f4 = 8 KB per buffer per operand; total 32 KB.
    __shared__ float4 wls[2][512];
    __shared__ float4 xls[2][512];

    const float4* __restrict__ x4 = (const float4*)x;
    const float4* __restrict__ w4 = (const float4*)w;

    // Stage c-chunk ci (c = 4ci..4ci+3) into buffer `buf`: per operand
    // 8 KB = 8 wave-instrs (1 per wave). Wave wv covers rows 8wv..8wv+7
    // (128 B each); LDS dest wave-uniform base + lane*16 (linear); lane
    // l -> row 8wv + (l>>3), col l&7.
    const int srow = wv * 8 + (lane >> 3);  // 0..63 = hi*4 + cl
    const int shi  = srow >> 2;
    const int scl  = srow & 3;
    const int sq   = lane & 7;
    auto stage = [&](int buf, int ci) {
        const int c = ci * 4 + scl;
        const float4* srcw =
            &w4[((o0 + shi) * CIN + c) * RS4 + pf0 + sq];
        __builtin_amdgcn_global_load_lds(
            (const __attribute__((address_space(1))) void*)srcw,
            (__attribute__((address_space(3))) void*)&wls[buf][wv * 64],
            16, 0, 0);
        const float4* srcx =
            &x4[(shi * CIN + c) * RS4 + pf0 + sq];
        __builtin_amdgcn_global_load_lds(
            (const __attribute__((address_space(1))) void*)srcx,
            (__attribute__((address_space(3))) void*)&xls[buf][wv * 64],
            16, 0, 0);
    };

    float acc[4][4] = {};                   // [bi][oi], carried over ci

    stage(0, 0);
    __syncthreads();   // vmcnt drain: buffer 0 staged

    #pragma unroll 1
    for (int ci = 0; ci < 8; ++ci) {
        if (ci < 7) stage((ci + 1) & 1, ci + 1);   // async prefetch
        const int buf = ci & 1;
        // compute: LDS only; this thread's single c this chunk (cl = cs).
        // x reads: per wave two 512 B contiguous runs -> conflict-free;
        // w reads: 512 B run, 2-way same-address broadcast -> free.
        float4 xv[4], wq[4];
        #pragma unroll
        for (int bi = 0; bi < 4; ++bi)
            xv[bi] = xls[buf][((g * 4 + bi) * 4 + cs) * 8 + p];
        #pragma unroll
        for (int oi = 0; oi < 4; ++oi)
            wq[oi] = wls[buf][((oq * 4 + oi) * 4 + cs) * 8 + p];
        #pragma unroll
        for (int bi = 0; bi < 4; ++bi)
            #pragma unroll
            for (int oi = 0; oi < 4; ++oi)
                acc[bi][oi] += xv[bi].x * wq[oi].x + xv[bi].y * wq[oi].y +
                               xv[bi].z * wq[oi].z + xv[bi].w * wq[oi].w;
        // readers done with buf (iter ci+1's stage overwrites it) AND
        // prefetch for ci+1 drained. Not needed after the last iter.
        if (ci < 7) __syncthreads();
    }

    // c-reduction over cs (lane bits 3-4): butterfly shfl, 4-way.
    #pragma unroll
    for (int bi = 0; bi < 4; ++bi)
        #pragma unroll
        for (int oi = 0; oi < 4; ++oi) {
            acc[bi][oi] += __shfl_xor(acc[bi][oi], 8, 64);
            acc[bi][oi] += __shfl_xor(acc[bi][oi], 16, 64);
        }

    const float scale = 0.17677669529663687f;  // 1/sqrt(32)
    if (cs == 0) {
        // lanes p=0..7 -> 32 B contiguous store per (bi,oi) per group;
        // adjacent pc blocks (same XCD) complete the 64 B lines in L2.
        #pragma unroll
        for (int bi = 0; bi < 4; ++bi)
            #pragma unroll
            for (int oi = 0; oi < 4; ++oi)
                out[((size_t)(4 * g + bi) * COUT + o0 + 4 * oq + oi) * OUT_DIM
                    + pc * 8 + p] = acc[bi][oi] * scale;
    }
}

extern "C" void kernel_launch(void* const* d_in, const int* in_sizes, int n_in,
                              void* d_out, int out_size, void* d_ws, size_t ws_size,
                              hipStream_t stream) {
    const float* x = (const float*)d_in[0];   // [16][32][4096] fp32
    const float* w = (const float*)d_in[1];   // [64][32][4096] fp32
    float* out = (float*)d_out;               // [16][64][1024] fp32

    nolc1d_kernel<<<dim3(512), dim3(512), 0, stream>>>(x, w, out);
}